// Round 1
// baseline (3093.900 us; speedup 1.0000x reference)
//
#include <hip/hip_runtime.h>
#include <math.h>

// TNO block, fully frequency-domain pipeline.
// Conventions: "forward-normalized" spectra A[ky][kx] (ky<128, kx<=64):
//   x[y][n] = sum_full A e^{+2pi i (ky y + kx n)/128},  A = rfft2(x, norm='forward').
// irfft2 semantics (Im dropped at kx=0 and kx=Nyq after ky-ifft) are implemented
// exactly by y = Re( sum_ky sum_{kx<=Nyq} w(kx) A e^{+i...} ), w=1 at 0/Nyq else 2.

#define F128 8320   // 128*65

__device__ __forceinline__ void blockReduce2(float& a, float& b, float* red){
  int tid = threadIdx.x;
  red[tid] = a; red[256+tid] = b;
  __syncthreads();
  for(int off=128; off>0; off>>=1){
    if(tid<off){ red[tid]+=red[tid+off]; red[256+tid]+=red[256+tid+off]; }
    __syncthreads();
  }
  a = red[0]; b = red[256];
  __syncthreads();
}

// ---------------- DFT twiddle tables: C[a*128+b]=cos(2pi ab/128), S likewise --------
__global__ void k_tables(float* __restrict__ Ct, float* __restrict__ St){
  int a = blockIdx.x, b = threadIdx.x;
  int p = (a*b)&127;
  float t = (float)p * (1.0f/64.0f);     // angle = pi*t
  Ct[a*128+b] = cospif(t);
  St[a*128+b] = sinpif(t);
}

// ---------------- rfft2 (+optional per-map instance norm folded in) ----------------
// out A = scale * DFT(x), scale = rs*w/16384 (donorm) else 1/16384 ; DC forced to b.
__global__ __launch_bounds__(256) void k_rfft2(
    const float* __restrict__ xin, float* __restrict__ Are, float* __restrict__ Aim,
    const float* __restrict__ Ct, const float* __restrict__ St,
    const float* __restrict__ wv, const float* __restrict__ bv,
    int wmask, int donorm)
{
  __shared__ float xs[128*129];      // transposed + padded: xs[x*129+y]
  __shared__ float Rre[2048], Rim[2048];
  __shared__ float red[512];
  const int m = blockIdx.x, tid = threadIdx.x;
  const float* xp = xin + (size_t)m*16384;
  float s1=0.f, s2=0.f;
  for(int i=tid;i<16384;i+=256){
    float v = xp[i];
    xs[(i&127)*129 + (i>>7)] = v;
    s1 += v; s2 += v*v;
  }
  blockReduce2(s1, s2, red);
  float mu = s1*(1.0f/16384.0f);
  float var = s2*(1.0f/16384.0f) - mu*mu;
  float rs = rsqrtf(var + 1e-5f);
  float scale = 1.0f/16384.0f, dcval = 0.f;
  if(donorm){ scale *= rs*wv[m & wmask]; dcval = bv[m & wmask]; }

  for(int pb=0; pb<65; pb+=16){
    const int psz = (pb==64)?1:16;
    __syncthreads();
    // phase A: row DFT (over x) for panel columns kx = pb..pb+psz-1
    for(int idx=tid; idx<(psz<<7); idx+=256){
      const int kxl = idx>>7, y = idx&127, kx = pb+kxl;
      const float* ct = Ct + kx*128;
      const float* st = St + kx*128;
      float ar=0.f, ai=0.f;
      for(int x=0;x<128;x++){
        float v = xs[x*129+y];
        ar += v*ct[x];
        ai -= v*st[x];
      }
      Rre[kxl*128+y]=ar; Rim[kxl*128+y]=ai;
    }
    __syncthreads();
    // phase B: column DFT (over y) ; thread owns ky, 8 kxl's
    const int ky = tid&127, grp = tid>>7;
    float accr[8], acci[8];
    #pragma unroll
    for(int q=0;q<8;q++){accr[q]=0.f;acci[q]=0.f;}
    for(int y=0;y<128;y++){
      float cr = Ct[y*128+ky], sn = St[y*128+ky];
      #pragma unroll
      for(int q=0;q<8;q++){
        int kxl = grp + (q<<1);
        if(kxl<psz){
          float br = Rre[kxl*128+y], bi = Rim[kxl*128+y];
          accr[q] += br*cr + bi*sn;
          acci[q] += bi*cr - br*sn;
        }
      }
    }
    __syncthreads();
    // stage to LDS for coalesced global write
    #pragma unroll
    for(int q=0;q<8;q++){
      int kxl = grp + (q<<1);
      if(kxl<psz){ Rre[ky*16+kxl] = accr[q]; Rim[ky*16+kxl] = acci[q]; }
    }
    __syncthreads();
    for(int idx=tid; idx<(psz<<7); idx+=256){
      int kyy, kxl;
      if(psz==16){ kyy = idx>>4; kxl = idx&15; } else { kyy = idx; kxl = 0; }
      int kx = pb + kxl;
      float outr = Rre[kyy*16+kxl]*scale;
      float outi = Rim[kyy*16+kxl]*scale;
      if(donorm && kyy==0 && kx==0){ outr=dcval; outi=0.f; }
      Are[(size_t)m*F128 + kyy*65 + kx] = outr;
      Aim[(size_t)m*F128 + kyy*65 + kx] = outi;
    }
  }
}

// ---------------- irfft2 with fused epilogues ----------------
// mode 0: y = IN(y + addsrc)*w+b           (attn path; addsrc=x)
// mode 1: y = gelu(y)                      (h1 path)
// mode 2: y = IN(y)*w+b + addsrc           (final; addsrc=attn)
__global__ __launch_bounds__(256) void k_irfft2(
    const float* __restrict__ Are, const float* __restrict__ Aim,
    const float* __restrict__ Ct, const float* __restrict__ St,
    const int mode,
    const float* __restrict__ addsrc,
    const float* __restrict__ wv, const float* __restrict__ bv, const int wmask,
    float* __restrict__ outp)
{
  __shared__ float Asre[F128], Asim[F128];
  __shared__ float Vre[2048], Vim[2048];
  __shared__ float red[512];
  const int m = blockIdx.x, tid = threadIdx.x;
  for(int i=tid;i<F128;i+=256){
    Asre[i] = Are[(size_t)m*F128+i];
    Asim[i] = Aim[(size_t)m*F128+i];
  }
  float yacc[64];
  #pragma unroll
  for(int i=0;i<64;i++) yacc[i]=0.f;
  const int n = tid&127, mgrp = tid>>7;   // thread owns column n, rows mgrp*64..+63
  __syncthreads();
  for(int pb=0; pb<65; pb+=16){
    const int psz = (pb==64)?1:16;
    {  // phase A: V[kxl][mm] = sum_ky A e^{+i 2pi ky mm/128}, then *omega
      const int mm = tid&127, grp = tid>>7;
      float vr[8], vi[8];
      #pragma unroll
      for(int q=0;q<8;q++){vr[q]=0.f;vi[q]=0.f;}
      for(int ky=0;ky<128;ky++){
        float cr = Ct[ky*128+mm], sn = St[ky*128+mm];
        #pragma unroll
        for(int q=0;q<8;q++){
          int kxl = grp + (q<<1);
          if(kxl<psz){
            int kx = pb+kxl;
            float ar = Asre[ky*65+kx], ai = Asim[ky*65+kx];
            vr[q] += ar*cr - ai*sn;
            vi[q] += ar*sn + ai*cr;
          }
        }
      }
      #pragma unroll
      for(int q=0;q<8;q++){
        int kxl = grp + (q<<1);
        if(kxl<psz){
          int kx = pb+kxl;
          float w = (kx==0||kx==64)?1.0f:2.0f;
          Vre[kxl*128+mm]=vr[q]*w;
          Vim[kxl*128+mm]=vi[q]*w;
        }
      }
    }
    __syncthreads();
    // phase B: y(row,n) += Re(V * e^{+i 2pi kx n/128})
    for(int kxl=0;kxl<psz;kxl++){
      int kx = pb+kxl;
      float cr = Ct[kx*128+n], sn = St[kx*128+n];
      const float* vrp = Vre + kxl*128 + (mgrp<<6);
      const float* vip = Vim + kxl*128 + (mgrp<<6);
      #pragma unroll 8
      for(int i=0;i<64;i++) yacc[i] += vrp[i]*cr - vip[i]*sn;
    }
    __syncthreads();
  }
  const size_t mbase = (size_t)m*16384;
  if(mode==1){
    for(int i=0;i<64;i++){
      float v = yacc[i];
      outp[mbase + ((((mgrp<<6)+i))<<7) + n] = 0.5f*v*(1.0f+erff(v*0.70710678118f));
    }
  } else {
    float s1=0.f, s2=0.f;
    if(mode==0){
      for(int i=0;i<64;i++){
        float v = yacc[i] + addsrc[mbase + ((((mgrp<<6)+i))<<7) + n];
        yacc[i]=v; s1+=v; s2+=v*v;
      }
    } else {
      for(int i=0;i<64;i++){ float v=yacc[i]; s1+=v; s2+=v*v; }
    }
    blockReduce2(s1,s2,red);
    float mu = s1*(1.0f/16384.0f);
    float var = s2*(1.0f/16384.0f)-mu*mu;
    float rs = rsqrtf(var+1e-5f);
    float w = wv[m&wmask], b = bv[m&wmask];
    if(mode==0){
      for(int i=0;i<64;i++)
        outp[mbase + ((((mgrp<<6)+i))<<7) + n] = (yacc[i]-mu)*rs*w + b;
    } else {
      for(int i=0;i<64;i++){
        size_t o = mbase + ((((mgrp<<6)+i))<<7) + n;
        outp[o] = (yacc[i]-mu)*rs*w + b + addsrc[o];
      }
    }
  }
}

// ---------------- K/Q spectra on the 64-grid (trunc + corners + Pi proj) ----------
__global__ __launch_bounds__(256) void k_build_qk(
  const float* __restrict__ Xnre, const float* __restrict__ Xnim,
  const float* __restrict__ kqv_wr, const float* __restrict__ kqv_wi,
  const float* __restrict__ kqv_bias, const float* __restrict__ kqv_sw, const float* __restrict__ kqv_sb,
  float* __restrict__ Qre, float* __restrict__ Qim,
  float* __restrict__ Kre, float* __restrict__ Kim)
{
  __shared__ float Tre[2112], Tim[2112];
  __shared__ float Qr[2112], Qi[2112], Kr[2112], Ki[2112];
  const int bid = blockIdx.x;
  const int m = bid>>3, o = bid&7;
  const int tid = threadIdx.x;
  for(int j=tid;j<2112;j+=256){
    int r = j/33, c = j - r*33;
    int ky = (r<32)? r : r+64;          // rows 32..63 <- 96..127
    Tre[j] = Xnre[(size_t)m*F128 + ky*65 + c];
    Tim[j] = Xnim[(size_t)m*F128 + ky*65 + c];
  }
  __syncthreads();
  const float swK = kqv_sw[o];          // layer 0 = K
  const float swQ = kqv_sw[8+o];        // layer 1 = Q
  for(int j=tid;j<2112;j+=256){
    int r = j/33, c = j - r*33;
    float tr = Tre[j], ti = Tim[j];
    float kr = swK*tr, ki2 = swK*ti;
    float qr = swQ*tr, qi = swQ*ti;
    if(c<8){
      int wrow = (r<8)? r : ((r>=56)? 8+(r-56) : -1);
      if(wrow>=0){
        float wkr = kqv_wr[(o*16+wrow)*8+c],      wki = kqv_wi[(o*16+wrow)*8+c];
        kr += wkr*tr - wki*ti; ki2 += wkr*ti + wki*tr;
        float wqr = kqv_wr[((8+o)*16+wrow)*8+c],  wqi = kqv_wi[((8+o)*16+wrow)*8+c];
        qr += wqr*tr - wqi*ti; qi += wqr*ti + wqi*tr;
      }
    }
    if(j==0){
      kr += kqv_bias[o]   + kqv_sb[o];
      qr += kqv_bias[8+o] + kqv_sb[8+o];
    }
    Kr[j]=kr; Ki[j]=ki2; Qr[j]=qr; Qi[j]=qi;
  }
  __syncthreads();
  const size_t obase = ((size_t)(m*8+o))*2112;
  for(int j=tid;j<2112;j+=256){
    int r = j/33, c = j - r*33;
    float kr=Kr[j], ki2=Ki[j], qr=Qr[j], qi=Qi[j];
    float wsc = 128.0f;                           // omega*64 folded into K
    if(c==0 || c==32){                            // Hermitian projection Pi
      int pj = ((64-r)&63)*33 + c;
      kr = 0.5f*(Kr[j]+Kr[pj]); ki2 = 0.5f*(Ki[j]-Ki[pj]);
      qr = 0.5f*(Qr[j]+Qr[pj]); qi  = 0.5f*(Qi[j]-Qi[pj]);
      wsc = 64.0f;
    }
    Qre[obase+j]=qr; Qim[obase+j]=qi;
    Kre[obase+j]=kr*wsc; Kim[obase+j]=ki2*wsc;
  }
}

// ---------------- scores via Parseval: S = sum(QrKr+QiKi) (K pre-scaled) ----------
__global__ __launch_bounds__(256) void k_scores(
  const float* __restrict__ Qre, const float* __restrict__ Qim,
  const float* __restrict__ Kre, const float* __restrict__ Kim,
  float* __restrict__ P)
{
  __shared__ float Klr[128*65], Kli[128*65];
  __shared__ float Qlr[8*65],  Qli[8*65];
  const int bid = blockIdx.x;
  const int b = bid>>7, h = (bid>>4)&7, tt = bid&15;
  const int tid = threadIdx.x;
  const int ts = tid>>5, ss = tid&31;
  float acc[4] = {0.f,0.f,0.f,0.f};
  for(int ch=0; ch<33; ch++){
    const int fb = ch*64;
    __syncthreads();
    for(int idx=tid; idx<128*64; idx+=256){
      int s = idx>>6, fl = idx&63;
      size_t off = ((size_t)((b*128+s)*8+h))*2112 + fb + fl;
      Klr[s*65+fl] = Kre[off]; Kli[s*65+fl] = Kim[off];
    }
    for(int idx=tid; idx<8*64; idx+=256){
      int t = idx>>6, fl = idx&63;
      size_t off = ((size_t)((b*128+tt*8+t)*8+h))*2112 + fb + fl;
      Qlr[t*65+fl] = Qre[off]; Qli[t*65+fl] = Qim[off];
    }
    __syncthreads();
    for(int f=0; f<64; f++){
      float qr = Qlr[ts*65+f], qi = Qli[ts*65+f];
      #pragma unroll
      for(int k=0;k<4;k++){
        int s = k*32+ss;
        acc[k] += qr*Klr[s*65+f] + qi*Kli[s*65+f];
      }
    }
  }
  const int t = tt*8+ts;
  #pragma unroll
  for(int k=0;k<4;k++){
    int s = k*32+ss;
    P[((size_t)((b*8+h)*128+t))*128 + s] = acc[k];
  }
}

__global__ __launch_bounds__(64) void k_softmax(float* __restrict__ P){
  const int row = blockIdx.x, tid = threadIdx.x;
  float* p = P + (size_t)row*128;
  float v0 = p[tid], v1 = p[tid+64];
  float mx = fmaxf(v0,v1);
  for(int off=32; off; off>>=1) mx = fmaxf(mx, __shfl_xor(mx, off));
  float e0 = expf(v0-mx), e1 = expf(v1-mx);
  float s = e0+e1;
  for(int off=32; off; off>>=1) s += __shfl_xor(s, off);
  float inv = 1.0f/s;
  p[tid] = e0*inv; p[tid+64] = e1*inv;
}

// Peff[b][t][s] = sum_h p_sw[h]*sv[h]*P[b,h,t,s]
__global__ __launch_bounds__(256) void k_peff(const float* __restrict__ P,
   const float* __restrict__ p_sw, const float* __restrict__ kqv_sw,
   float* __restrict__ Peff)
{
  const int i = blockIdx.x*256 + threadIdx.x;   // < 32768
  const int b = i>>14, rem = i&16383;
  float acc=0.f;
  for(int hh=0; hh<8; hh++){
    float a = p_sw[hh]*kqv_sw[16+hh];
    acc += a * P[(((size_t)(b*8+hh))<<14) + rem];
  }
  Peff[i] = acc;
}

// gather Xn at proj-corner modes Omega_p (rows 0..15 & 112..127, cols 0..15)
__global__ __launch_bounds__(256) void k_gather(
   const float* __restrict__ Xnre, const float* __restrict__ Xnim,
   float* __restrict__ Xpr, float* __restrict__ Xpi)
{
  const int m = blockIdx.x, tid = threadIdx.x;
  for(int j=tid;j<512;j+=256){
    int r = j>>4, c = j&15;
    int ky = (r<16)? r : 96+r;
    size_t f = (size_t)m*F128 + ky*65 + c;
    Xpr[m*512+j] = Xnre[f]; Xpi[m*512+j] = Xnim[f];
  }
}

// Zp[b][o][c][j] = sum_s P[b,o,c,s] * Xn|Omega_p[b,s,j]
__global__ __launch_bounds__(256) void k_zp(const float* __restrict__ P,
  const float* __restrict__ Xpr, const float* __restrict__ Xpi,
  float* __restrict__ Zr, float* __restrict__ Zi)
{
  __shared__ float Pt[2048];
  const int bid = blockIdx.x;
  const int b = bid>>6, o = (bid>>3)&7, ct = bid&7;
  const int tid = threadIdx.x;
  for(int idx=tid; idx<2048; idx+=256){
    int cl = idx>>7, s = idx&127;
    Pt[cl*128+s] = P[((size_t)((b*8+o)*128 + ct*16+cl))*128 + s];
  }
  __syncthreads();
  for(int it=0; it<2; it++){
    int j = tid + it*256;
    float ar[16], ai[16];
    #pragma unroll
    for(int c=0;c<16;c++){ ar[c]=0.f; ai[c]=0.f; }
    for(int s=0;s<128;s++){
      float xr = Xpr[(b*128+s)*512 + j];
      float xi = Xpi[(b*128+s)*512 + j];
      #pragma unroll
      for(int c=0;c<16;c++){
        float pv = Pt[c*128+s];
        ar[c] += pv*xr; ai[c] += pv*xi;
      }
    }
    #pragma unroll
    for(int c=0;c<16;c++){
      size_t off = ((size_t)((b*8+o)*128 + ct*16+c))*512 + j;
      Zr[off]=ar[c]; Zi[off]=ai[c];
    }
  }
}

// B[b,c][f] = sum_s Peff[b,c,s] * Xn[b,s][f]   (full grid heavy term)
__global__ __launch_bounds__(256) void k_big(const float* __restrict__ Peff,
  const float* __restrict__ Xnre, const float* __restrict__ Xnim,
  float* __restrict__ Br, float* __restrict__ Bi)
{
  __shared__ float Pt[2048];
  const int bid = blockIdx.x;
  const int b = bid>>6, ct = (bid>>3)&7, fc = bid&7;
  const int tid = threadIdx.x;
  for(int idx=tid; idx<2048; idx+=256){
    int cl = idx>>7, s = idx&127;
    Pt[cl*128+s] = Peff[((size_t)(b*128 + ct*16+cl))*128 + s];
  }
  __syncthreads();
  const int fb = fc*1040;
  for(int it=0; it<5; it++){
    int j = fb + tid + it*256;
    if(j >= fb+1040) break;
    float ar[16], ai[16];
    #pragma unroll
    for(int c=0;c<16;c++){ ar[c]=0.f; ai[c]=0.f; }
    for(int s=0;s<128;s++){
      float xr = Xnre[(size_t)(b*128+s)*F128 + j];
      float xi = Xnim[(size_t)(b*128+s)*F128 + j];
      #pragma unroll
      for(int c=0;c<16;c++){
        float pv = Pt[c*128+s];
        ar[c] += pv*xr; ai[c] += pv*xi;
      }
    }
    #pragma unroll
    for(int c=0;c<16;c++){
      size_t off = (size_t)(b*128+ct*16+c)*F128 + j;
      Br[off]=ar[c]; Bi[off]=ai[c];
    }
  }
}

// corner corrections: + sum_o psw*Pi(Wv.Zv) + sum_o Wp.(attn_freq|Omega_p) + DC
__global__ __launch_bounds__(256) void k_corr(
  const float* __restrict__ Zr, const float* __restrict__ Zi,
  const float* __restrict__ kqv_wr, const float* __restrict__ kqv_wi,
  const float* __restrict__ kqv_bias, const float* __restrict__ kqv_sw, const float* __restrict__ kqv_sb,
  const float* __restrict__ p_wr, const float* __restrict__ p_wi,
  const float* __restrict__ p_bias, const float* __restrict__ p_sw, const float* __restrict__ p_sb,
  float* __restrict__ Br, float* __restrict__ Bi)
{
  const int m = blockIdx.x;          // b*128+c
  const int b = m>>7, cix = m&127;
  const int tid = threadIdx.x;
  for(int j=tid; j<512; j+=256){
    int r = j>>4, c = j&15;
    int ky = (r<16)? r : 96+r;
    float accr=0.f, acci=0.f;
    int rp = -1;
    if(c==0){ int kyp = (128-ky)&127; rp = (kyp<16)? kyp : ((kyp>=112)? kyp-96 : -1); }
    for(int o=0;o<8;o++){
      size_t zoff = ((size_t)((b*8+o)*128 + cix))*512;
      float zr = Zr[zoff+j], zi = Zi[zoff+j];
      float cvr=0.f, cvi=0.f;
      bool inV = (c<8) && (ky<8 || ky>=120);
      if(inV){
        int vrow = (ky<8)? ky : 8+(ky-120);
        float wr = kqv_wr[((16+o)*16+vrow)*8+c], wi = kqv_wi[((16+o)*16+vrow)*8+c];
        cvr = wr*zr - wi*zi; cvi = wr*zi + wi*zr;
      }
      float ar = cvr, ai = cvi;
      if(c==0){
        float pvr=0.f, pvi=0.f;
        int kyp = (128-ky)&127;
        bool pInV = (kyp<8 || kyp>=120);
        if(pInV && rp>=0){
          int vrow = (kyp<8)? kyp : 8+(kyp-120);
          float zr2 = Zr[zoff + rp*16], zi2 = Zi[zoff + rp*16];
          float wr = kqv_wr[((16+o)*16+vrow)*8], wi = kqv_wi[((16+o)*16+vrow)*8];
          pvr = wr*zr2 - wi*zi2; pvi = wr*zi2 + wi*zr2;
        }
        ar = 0.5f*(cvr + pvr);
        ai = 0.5f*(cvi - pvi);
      }
      float sv = kqv_sw[16+o];
      float Dv = kqv_bias[16+o] + kqv_sb[16+o];
      float atr = sv*zr + ar + ((j==0)? Dv : 0.f);
      float ati = sv*zi + ai;
      float psw = p_sw[o];
      accr += psw*ar;  acci += psw*ai;
      float wpr = p_wr[(o*32+r)*16+c], wpi = p_wi[(o*32+r)*16+c];
      accr += wpr*atr - wpi*ati;
      acci += wpr*ati + wpi*atr;
      if(j==0) accr += psw*Dv;
    }
    if(j==0) accr += p_bias[0] + p_sb[0];
    size_t f = (size_t)m*F128 + ky*65 + c;
    Br[f] += accr; Bi[f] += acci;
  }
}

// mixer layer: out[g,o] = IN(spectral(h))_freq + skip_freq   (full grid)
__global__ __launch_bounds__(256) void k_mix(
  const float* __restrict__ Hre, const float* __restrict__ Him,
  const float* __restrict__ wr0, const float* __restrict__ wi0,
  const float* __restrict__ msw, const float* __restrict__ msb,
  float* __restrict__ Ore, float* __restrict__ Oim)
{
  __shared__ float scr[512], sci[512];
  __shared__ float red[512];
  const int bid = blockIdx.x;
  const int g = bid>>2, o = bid&3;
  const int tid = threadIdx.x;
  for(int j=tid;j<512;j+=256){
    int r=j>>4, c=j&15;
    int ky = (r<16)? r : 96+r;
    int f = ky*65+c;
    float ar=0.f, ai=0.f;
    for(int i2=0;i2<4;i2++){
      float hr = Hre[(size_t)(g*4+i2)*F128+f], hi = Him[(size_t)(g*4+i2)*F128+f];
      float wr = wr0[((i2*4+o)*32+r)*16+c],   wi = wi0[((i2*4+o)*32+r)*16+c];
      ar += wr*hr - wi*hi; ai += wr*hi + wi*hr;
    }
    scr[j]=ar; sci[j]=ai;
  }
  __syncthreads();
  // var of the (Pi-projected) spectral field, excluding DC
  float vs=0.f, dummy=0.f;
  for(int j=tid;j<512;j+=256){
    int c=j&15;
    if(c>=1) vs += 2.0f*(scr[j]*scr[j]+sci[j]*sci[j]);
  }
  if(tid<32){
    int ky = (tid<16)? (tid+1) : (96+tid);     // {1..16} U {112..127}
    float ar=0.f, ai=0.f;
    if(ky<16){ ar=scr[ky*16]; ai=sci[ky*16]; }
    else if(ky>=112){ int r=ky-96; ar=scr[r*16]; ai=sci[r*16]; }
    int kyp = 128-ky;
    float br2=0.f, bi2=0.f;
    if(kyp<16){ br2=scr[kyp*16]; bi2=sci[kyp*16]; }
    else if(kyp>=112){ int r=kyp-96; br2=scr[r*16]; bi2=sci[r*16]; }
    float pr = 0.5f*(ar+br2), pi = 0.5f*(ai-bi2);
    vs += pr*pr + pi*pi;
  }
  blockReduce2(vs, dummy, red);
  float rs2 = rsqrtf(vs + 1e-5f);
  for(int f=tid; f<F128; f+=256){
    int ky = f/65, c = f - ky*65;
    float skr=0.f, ski=0.f;
    for(int i2=0;i2<4;i2++){
      float sw = msw[o*4+i2];
      skr += sw*Hre[(size_t)(g*4+i2)*F128+f];
      ski += sw*Him[(size_t)(g*4+i2)*F128+f];
    }
    if(f==0) skr += msb[o];
    if(c<16){
      int r = (ky<16)? ky : ((ky>=112)? ky-96 : -1);
      if(r>=0){
        int j = r*16+c;
        if(j!=0){ skr += rs2*scr[j]; ski += rs2*sci[j]; }
      }
    }
    Ore[(size_t)(g*4+o)*F128+f] = skr;
    Oim[(size_t)(g*4+o)*F128+f] = ski;
  }
}

extern "C" void kernel_launch(void* const* d_in, const int* in_sizes, int n_in,
                              void* d_out, int out_size, void* d_ws, size_t ws_size,
                              hipStream_t stream)
{
  const float* x        = (const float*)d_in[0];
  const float* norm1_w  = (const float*)d_in[1];
  const float* norm1_b  = (const float*)d_in[2];
  const float* kqv_wr   = (const float*)d_in[3];
  const float* kqv_wi   = (const float*)d_in[4];
  const float* kqv_bias = (const float*)d_in[5];
  const float* kqv_sw   = (const float*)d_in[6];
  const float* kqv_sb   = (const float*)d_in[7];
  const float* p_wr     = (const float*)d_in[8];
  const float* p_wi     = (const float*)d_in[9];
  const float* p_bias   = (const float*)d_in[10];
  const float* p_sw     = (const float*)d_in[11];
  const float* p_sb     = (const float*)d_in[12];
  const float* attn_norm_w = (const float*)d_in[13];
  const float* attn_norm_b = (const float*)d_in[14];
  const float* norm2_w  = (const float*)d_in[15];
  const float* norm2_b  = (const float*)d_in[16];
  const float* mix_wr   = (const float*)d_in[17];
  const float* mix_wi   = (const float*)d_in[18];
  // mix_bias (d_in[19]) only shifts the spectral mean which IN removes -> unused
  const float* mix_sw   = (const float*)d_in[20];
  const float* mix_sb   = (const float*)d_in[21];
  const float* mon_w    = (const float*)d_in[22];
  const float* mon_b    = (const float*)d_in[23];
  float* out = (float*)d_out;

  const size_t NEED = (size_t)28442624 * sizeof(float);
  if(ws_size < NEED) return;

  float* ws = (float*)d_ws;
  size_t off = 0;
  float* Ct   = ws + off; off += 16384;
  float* St   = ws + off; off += 16384;
  float* Xnre = ws + off; off += (size_t)256*F128;
  float* Xnim = ws + off; off += (size_t)256*F128;
  float* pool = ws + off; off += 17301504;
  float* P    = ws + off; off += 262144;
  float* Peff = ws + off; off += 32768;
  float* Xpr  = ws + off; off += 131072;
  float* Xpi  = ws + off; off += 131072;
  float* Zr   = ws + off; off += 1048576;
  float* Zi   = ws + off; off += 1048576;
  float* attn = ws + off; off += 4194304;

  float* Qre = pool;
  float* Qim = pool + 4325376;
  float* Kre = pool + 8650752;
  float* Kim = pool + 12976128;
  float* Br  = pool;                    // after scores (Q dead)
  float* Bi  = pool + 2129920;
  float* h1fre = pool + 4325376;        // Qim chunk
  float* h1fim = pool + 4325376 + 2129920;
  float* h1g   = pool + 8650752;        // Kre chunk
  float* h1gfre= pool;                  // B dead after attn irfft
  float* h1gfim= pool + 2129920;
  float* h2fre = pool + 12976128;       // Kim chunk
  float* h2fim = pool + 12976128 + 2129920;
  float* h0fre = Xnre;                  // Xn dead once B/Zp consumed
  float* h0fim = Xnim;

  k_tables<<<dim3(128), dim3(128), 0, stream>>>(Ct, St);
  // tok_n spectra (instance-norm folded)
  k_rfft2<<<dim3(256), dim3(256), 0, stream>>>(x, Xnre, Xnim, Ct, St, norm1_w, norm1_b, 0, 1);
  // K,Q on 64-grid
  k_build_qk<<<dim3(2048), dim3(256), 0, stream>>>(Xnre, Xnim, kqv_wr, kqv_wi, kqv_bias, kqv_sw, kqv_sb,
                                                   Qre, Qim, Kre, Kim);
  k_scores<<<dim3(256), dim3(256), 0, stream>>>(Qre, Qim, Kre, Kim, P);
  k_softmax<<<dim3(2048), dim3(64), 0, stream>>>(P);
  k_peff<<<dim3(128), dim3(256), 0, stream>>>(P, p_sw, kqv_sw, Peff);
  k_gather<<<dim3(256), dim3(256), 0, stream>>>(Xnre, Xnim, Xpr, Xpi);
  k_zp<<<dim3(128), dim3(256), 0, stream>>>(P, Xpr, Xpi, Zr, Zi);
  k_big<<<dim3(128), dim3(256), 0, stream>>>(Peff, Xnre, Xnim, Br, Bi);
  k_corr<<<dim3(256), dim3(256), 0, stream>>>(Zr, Zi, kqv_wr, kqv_wi, kqv_bias, kqv_sw, kqv_sb,
                                              p_wr, p_wi, p_bias, p_sw, p_sb, Br, Bi);
  // attn = IN(irfft2(B) + tokens)
  k_irfft2<<<dim3(256), dim3(256), 0, stream>>>(Br, Bi, Ct, St, 0, x, attn_norm_w, attn_norm_b, 0, attn);
  // h0 spectra (norm2 folded)
  k_rfft2<<<dim3(256), dim3(256), 0, stream>>>(attn, h0fre, h0fim, Ct, St, norm2_w, norm2_b, 3, 1);
  // mixer layer 1 -> h1f ; gelu in spatial ; back to freq
  k_mix<<<dim3(256), dim3(256), 0, stream>>>(h0fre, h0fim, mix_wr, mix_wi, mix_sw, mix_sb, h1fre, h1fim);
  k_irfft2<<<dim3(256), dim3(256), 0, stream>>>(h1fre, h1fim, Ct, St, 1, (const float*)nullptr,
                                               (const float*)nullptr, (const float*)nullptr, 0, h1g);
  k_rfft2<<<dim3(256), dim3(256), 0, stream>>>(h1g, h1gfre, h1gfim, Ct, St,
                                               (const float*)nullptr, (const float*)nullptr, 0, 0);
  // mixer layer 2 -> h2f ; final: out = IN(irfft2(h2f))*mon + attn
  k_mix<<<dim3(256), dim3(256), 0, stream>>>(h1gfre, h1gfim, mix_wr+8192, mix_wi+8192, mix_sw+16, mix_sb+4,
                                             h2fre, h2fim);
  k_irfft2<<<dim3(256), dim3(256), 0, stream>>>(h2fre, h2fim, Ct, St, 2, attn, mon_w, mon_b, 3, out);
}